// Round 5
// baseline (558.702 us; speedup 1.0000x reference)
//
#include <hip/hip_runtime.h>
#include <stdint.h>

#define EMB 1024
#define SEQ 2048
#define NB 4
#define NH 16
#define HD 64
#define NGLOB 4
#define WIN 256
#define MTOT (NB*SEQ)   // 8192
#define NQKV (3*EMB)    // 3072

typedef __attribute__((ext_vector_type(8))) short bf16x8;
typedef __attribute__((ext_vector_type(4))) float f32x4;
typedef __attribute__((ext_vector_type(16))) float f32x16;
typedef unsigned short u16;
typedef unsigned int u32;

__device__ __forceinline__ u16 f2bf(float f) {
  u32 u = __builtin_bit_cast(u32, f);
  u += 0x7fffu + ((u >> 16) & 1u);
  return (u16)(u >> 16);
}

__device__ __forceinline__ float bf2f(u16 v) {
  u32 u = (u32)v << 16;
  return __builtin_bit_cast(float, u);
}

__device__ __forceinline__ u32 pack2bf(float a, float b) {
  return (u32)f2bf(a) | ((u32)f2bf(b) << 16);
}

#define MFMA16(a, b, c) __builtin_amdgcn_mfma_f32_16x16x32_bf16(a, b, c, 0, 0, 0)
#define MFMA32(a, b, c) __builtin_amdgcn_mfma_f32_32x32x16_bf16(a, b, c, 0, 0, 0)
#define GLD16(g, l) __builtin_amdgcn_global_load_lds( \
    (const __attribute__((address_space(1))) void*)(g), \
    (__attribute__((address_space(3))) void*)(l), 16, 0, 0)

// ---------------- cast fp32 -> bf16 (vectorized) ----------------
__global__ void k_cast(const float* __restrict__ in, u16* __restrict__ out, int n4) {
  int i = blockIdx.x * blockDim.x + threadIdx.x;
  if (i >= n4) return;
  float4 f = ((const float4*)in)[i];
  ushort4 o;
  o.x = f2bf(f.x); o.y = f2bf(f.y); o.z = f2bf(f.z); o.w = f2bf(f.w);
  ((ushort4*)out)[i] = o;
}

// ---------------- transpose + cast: w[R][C] -> wt[C][R] bf16 ----------------
__global__ void k_transpose_cast(const float* __restrict__ w, u16* __restrict__ wt,
                                 int R, int C) {
  __shared__ float tile[32][33];
  int c0 = blockIdx.x * 32, r0 = blockIdx.y * 32;
  int tx = threadIdx.x, ty = threadIdx.y;  // 32 x 8
  #pragma unroll
  for (int j = 0; j < 32; j += 8)
    tile[ty + j][tx] = w[(size_t)(r0 + ty + j) * C + (c0 + tx)];
  __syncthreads();
  #pragma unroll
  for (int j = 0; j < 32; j += 8)
    wt[(size_t)(c0 + ty + j) * R + (r0 + tx)] = f2bf(tile[tx][ty + j]);
}

// ---------------- 128x128 bf16 MFMA GEMM, K=1024, B given transposed ----------------
template <int EPI>
__global__ __launch_bounds__(256, 2) void k_gemm(
    const u16* __restrict__ A, const u16* __restrict__ Bt,
    const float* __restrict__ bias,
    u16* __restrict__ Qo, u16* __restrict__ Ko, u16* __restrict__ Vt,
    float* __restrict__ outp) {
  __shared__ __align__(16) u16 ldsA[128 * 64];
  __shared__ __align__(16) u16 ldsB[128 * 64];
  const int tid = threadIdx.x;
  const int w = tid >> 6, lane = tid & 63;
  const int wm = w >> 1, wn = w & 1;
  const int m0 = blockIdx.x * 128, n0 = blockIdx.y * 128;
  const int rq = lane & 15, g = lane >> 4;

  const int srow = lane >> 3;
  const int scol = ((lane & 7) ^ srow) << 3;

  f32x4 acc[4][4] = {};
  char* ldsAb = (char*)ldsA;
  char* ldsBb = (char*)ldsB;

  for (int k0 = 0; k0 < EMB; k0 += 64) {
    #pragma unroll
    for (int it = 0; it < 4; ++it) {
      int t = w * 4 + it;
      int row = t * 8 + srow;
      GLD16(A + (size_t)(m0 + row) * EMB + k0 + scol, ldsAb + t * 1024);
      GLD16(Bt + (size_t)(n0 + row) * EMB + k0 + scol, ldsBb + t * 1024);
    }
    __syncthreads();
    #pragma unroll
    for (int ks = 0; ks < 2; ++ks) {
      bf16x8 af[4], bfr[4];
      #pragma unroll
      for (int i = 0; i < 4; ++i) {
        int rowA = wm * 64 + i * 16 + rq;
        int off = (ks * 64 + (g << 4)) ^ ((rowA & 7) << 4);
        af[i] = *(const bf16x8*)(ldsAb + rowA * 128 + off);
        int rowB = wn * 64 + i * 16 + rq;
        int offb = (ks * 64 + (g << 4)) ^ ((rowB & 7) << 4);
        bfr[i] = *(const bf16x8*)(ldsBb + rowB * 128 + offb);
      }
      #pragma unroll
      for (int mi = 0; mi < 4; ++mi)
        #pragma unroll
        for (int ni = 0; ni < 4; ++ni)
          acc[mi][ni] = MFMA16(af[mi], bfr[ni], acc[mi][ni]);
    }
    __syncthreads();
  }

  #pragma unroll
  for (int ni = 0; ni < 4; ++ni) {
    int col = n0 + wn * 64 + ni * 16 + rq;
    float bv = bias[col];
    if (EPI == 0) {
      int part = col >> 10;
      int hh = (col & 1023) >> 6;
      int d = col & 63;
      #pragma unroll
      for (int mi = 0; mi < 4; ++mi) {
        #pragma unroll
        for (int i = 0; i < 4; ++i) {
          int m = m0 + wm * 64 + mi * 16 + g * 4 + i;
          int b = m >> 11, s = m & 2047;
          u16 val = f2bf(acc[mi][ni][i] + bv);
          size_t bh = (size_t)(b * NH + hh);
          if (part == 0)      Qo[(bh * SEQ + s) * HD + d] = val;
          else if (part == 1) Ko[(bh * SEQ + s) * HD + d] = val;
          else                Vt[(bh * HD + d) * SEQ + s] = val;
        }
      }
    } else {
      #pragma unroll
      for (int mi = 0; mi < 4; ++mi)
        #pragma unroll
        for (int i = 0; i < 4; ++i) {
          int m = m0 + wm * 64 + mi * 16 + g * 4 + i;
          outp[(size_t)m * EMB + col] = acc[mi][ni][i] + bv;
        }
    }
  }
}

// ---------------- flash attention ----------------
// gid < 1024 : global head task (bh, qt) split 4 ways across the block's
//              waves (flash-decoding); partials merged via LDS.
// gid >= 1024: 4 independent local-head tasks (<=9 chunks), direct write.
__global__ __launch_bounds__(256, 7) void k_attn(
    const u16* __restrict__ Q, const u16* __restrict__ K,
    const u16* __restrict__ Vt, u16* __restrict__ ctx) {
  __shared__ u16 Obuf[4][64][36];            // [wave][d][q] bf16 partials
  __shared__ float m_s[4][32], l_s[4][32];

  const int w = threadIdx.x >> 6, lane = threadIdx.x & 63;
  const int l31 = lane & 31;
  const int hi = lane >> 5;
  const bool hib = hi != 0;
  const int hi8 = hi * 8, hi4 = hi * 4;

  const int gid = blockIdx.x;
  const bool isglob = gid < 1024;

  int bh, qt, cstart, clen;   // chunk range [cstart, cstart+clen) of 32 keys
  if (isglob) {
    int bg = gid & 15;
    int j = gid >> 4;
    qt = ((j & 3) << 4) | (j >> 2);          // bijective, CU-balanced
    bh = (bg >> 2) * 16 + (bg & 3);
    int L = qt + 1;
    int base = L >> 2, rem = L & 3;
    clen = base + (w < rem ? 1 : 0);
    cstart = w * base + (w < rem ? w : rem);
  } else {
    int lidx = (gid - 1024) * 4 + w;         // 0..3071
    int bl = lidx >> 6;
    bh = (bl / 12) * 16 + 4 + (bl % 12);
    qt = lidx & 63;
    int qb_ = qt * 32;
    int klo = (qb_ > WIN) ? qb_ - WIN : 0;
    cstart = klo >> 5;
    clen = qt + 1 - cstart;
  }

  const int qb = qt * 32;
  const int h = bh & 15;
  const int b = bh >> 4;
  const bool isloc = !isglob;

  const u16* Qp = Q + (size_t)bh * SEQ * HD;
  const u16* Kp = K + (size_t)bh * SEQ * HD;
  const u16* Vp = Vt + (size_t)bh * HD * SEQ;

  const int q = qb + l31;

  // Q as B-operand: col=q (lane&31), k = j*16 + hi*8 + i
  bf16x8 qf[4];
  #pragma unroll
  for (int j = 0; j < 4; ++j)
    qf[j] = *(const bf16x8*)(Qp + (size_t)q * HD + j * 16 + hi8);

  f32x16 oacc[2] = {};
  float m = -__builtin_inff();
  float l = 0.f;

  int kc = cstart * 32;
  for (int it = 0; it < clen; ++it, kc += 32) {
    // S^T = K . Q^T
    f32x16 s = {};
    #pragma unroll
    for (int j = 0; j < 4; ++j) {
      bf16x8 kf = *(const bf16x8*)(Kp + (size_t)(kc + l31) * HD + j * 16 + hi8);
      s = MFMA32(kf, qf[j], s);
    }

    float p[16];
    float cmax = -__builtin_inff();
    #pragma unroll
    for (int r = 0; r < 16; ++r) {
      int key = kc + hi4 + (r & 3) + 8 * (r >> 2);
      float v = s[r] * 0.125f;
      bool msk = (key > q) || (isloc && (q - key > WIN));
      p[r] = msk ? -__builtin_inff() : v;
      cmax = fmaxf(cmax, p[r]);
    }
    cmax = fmaxf(cmax, __shfl_xor(cmax, 32));

    float mu;
    if (__any(cmax > m + 8.f)) {
      float mn = fmaxf(m, cmax);
      mu = (mn == -__builtin_inff()) ? 0.f : mn;
      float f = __expf(((m == -__builtin_inff()) ? mu : m) - mu);
      m = mn;
      l *= f;
      #pragma unroll
      for (int dt = 0; dt < 2; ++dt)
        #pragma unroll
        for (int r = 0; r < 16; ++r)
          oacc[dt][r] *= f;
    } else {
      mu = (m == -__builtin_inff()) ? 0.f : m;
    }

    float psum = 0.f;
    #pragma unroll
    for (int r = 0; r < 16; ++r) {
      p[r] = __expf(p[r] - mu);
      psum += p[r];
    }
    psum += __shfl_xor(psum, 32);
    l += psum;

    // P^T B-fragments: pack own pairs, exchange halves via shfl_xor(32)
    union { u32 u[4]; bf16x8 v; } pbf[2];
    #pragma unroll
    for (int sl = 0; sl < 2; ++sl) {
      int s8 = sl * 8;
      u32 X0 = pack2bf(p[s8 + 0], p[s8 + 1]);
      u32 X1 = pack2bf(p[s8 + 2], p[s8 + 3]);
      u32 X2 = pack2bf(p[s8 + 4], p[s8 + 5]);
      u32 X3 = pack2bf(p[s8 + 6], p[s8 + 7]);
      u32 oX0 = (u32)__shfl_xor((int)X0, 32);
      u32 oX1 = (u32)__shfl_xor((int)X1, 32);
      u32 oX2 = (u32)__shfl_xor((int)X2, 32);
      u32 oX3 = (u32)__shfl_xor((int)X3, 32);
      pbf[sl].u[0] = hib ? oX2 : X0;
      pbf[sl].u[1] = hib ? oX3 : X1;
      pbf[sl].u[2] = hib ? X2 : oX0;
      pbf[sl].u[3] = hib ? X3 : oX1;
    }

    // O^T += V^T . P^T
    #pragma unroll
    for (int dt = 0; dt < 2; ++dt) {
      #pragma unroll
      for (int sl = 0; sl < 2; ++sl) {
        bf16x8 vf = *(const bf16x8*)(Vp + (size_t)(dt * 32 + l31) * SEQ + kc + sl * 16 + hi8);
        oacc[dt] = MFMA32(vf, pbf[sl].v, oacc[dt]);
      }
    }
  }

  if (isglob) {
    // store partial (m, l, O^T bf16) to LDS
    if (hi == 0) { m_s[w][l31] = m; l_s[w][l31] = l; }
    #pragma unroll
    for (int dt = 0; dt < 2; ++dt)
      #pragma unroll
      for (int r = 0; r < 16; ++r) {
        int d = dt * 32 + hi4 + (r & 3) + 8 * (r >> 2);
        Obuf[w][d][l31] = f2bf(oacc[dt][r]);
      }
    __syncthreads();

    // merge: iterate q in groups of 4; thread handles one (q, d)
    const int tid = threadIdx.x;
    const int dd = tid & 63;
    const int qg = tid >> 6;           // 0..3
    #pragma unroll
    for (int i = 0; i < 8; ++i) {
      int qq = qg * 8 + i;
      float m0v = m_s[0][qq], m1v = m_s[1][qq], m2v = m_s[2][qq], m3v = m_s[3][qq];
      float M = fmaxf(fmaxf(m0v, m1v), fmaxf(m2v, m3v));
      float w0 = __expf(m0v - M), w1 = __expf(m1v - M);
      float w2 = __expf(m2v - M), w3 = __expf(m3v - M);
      float L = w0 * l_s[0][qq] + w1 * l_s[1][qq] + w2 * l_s[2][qq] + w3 * l_s[3][qq];
      float val = w0 * bf2f(Obuf[0][dd][qq]) + w1 * bf2f(Obuf[1][dd][qq]) +
                  w2 * bf2f(Obuf[2][dd][qq]) + w3 * bf2f(Obuf[3][dd][qq]);
      int s = qb + qq;
      ctx[(size_t)(b * SEQ + s) * EMB + h * HD + dd] = f2bf(val / L);
    }
  } else {
    // direct write
    float linv = 1.f / l;
    #pragma unroll
    for (int dt = 0; dt < 2; ++dt) {
      #pragma unroll
      for (int r = 0; r < 16; ++r) {
        int d = dt * 32 + hi4 + (r & 3) + 8 * (r >> 2);
        int e = h * HD + d;
        ctx[(size_t)(b * SEQ + q) * EMB + e] = f2bf(oacc[dt][r] * linv);
      }
    }
  }
}

extern "C" void kernel_launch(void* const* d_in, const int* in_sizes, int n_in,
                              void* d_out, int out_size, void* d_ws, size_t ws_size,
                              hipStream_t stream) {
  const float* x     = (const float*)d_in[0];
  const float* w_qkv = (const float*)d_in[1];
  const float* b_qkv = (const float*)d_in[2];
  const float* w_out = (const float*)d_in[3];
  const float* b_out = (const float*)d_in[4];
  float* out = (float*)d_out;

  char* ws = (char*)d_ws;
  u16* xb    = (u16*)(ws);
  u16* wqkvT = (u16*)(ws + (16ull << 20));
  u16* woutT = (u16*)(ws + (22ull << 20));
  u16* Qb    = (u16*)(ws + (24ull << 20));
  u16* Kb    = (u16*)(ws + (40ull << 20));
  u16* Vt    = (u16*)(ws + (56ull << 20));
  u16* ctx   = (u16*)(ws + (72ull << 20));

  k_cast<<<(MTOT * EMB / 4) / 256, 256, 0, stream>>>(x, xb, MTOT * EMB / 4);
  dim3 tb(32, 8);
  k_transpose_cast<<<dim3(NQKV / 32, EMB / 32), tb, 0, stream>>>(w_qkv, wqkvT, EMB, NQKV);
  k_transpose_cast<<<dim3(EMB / 32, EMB / 32), tb, 0, stream>>>(w_out, woutT, EMB, EMB);

  k_gemm<0><<<dim3(MTOT / 128, NQKV / 128), 256, 0, stream>>>(
      xb, wqkvT, b_qkv, Qb, Kb, Vt, nullptr);

  k_attn<<<dim3(1024 + 768), 256, 0, stream>>>(Qb, Kb, Vt, ctx);

  k_gemm<1><<<dim3(MTOT / 128, EMB / 128), 256, 0, stream>>>(
      ctx, woutT, b_out, nullptr, nullptr, nullptr, out);
}

// Round 7
// 205.050 us; speedup vs baseline: 2.7247x; 2.7247x over previous
//
#include <hip/hip_runtime.h>
#include <stdint.h>

#define EMB 1024
#define SEQ 2048
#define NB 4
#define NH 16
#define HD 64
#define NGLOB 4
#define WIN 256
#define MTOT (NB*SEQ)   // 8192
#define NQKV (3*EMB)    // 3072

// per-partial: O^T bf16 [64][32] (4096 B) + m[32] f32 + l[32] f32 (256 B)
#define PART_U16 2176   // 4352 bytes in u16 units

typedef __attribute__((ext_vector_type(8))) short bf16x8;
typedef __attribute__((ext_vector_type(4))) float f32x4;
typedef __attribute__((ext_vector_type(16))) float f32x16;
typedef unsigned short u16;
typedef unsigned int u32;

__device__ __forceinline__ u16 f2bf(float f) {
  u32 u = __builtin_bit_cast(u32, f);
  u += 0x7fffu + ((u >> 16) & 1u);
  return (u16)(u >> 16);
}

__device__ __forceinline__ float bf2f(u16 v) {
  u32 u = (u32)v << 16;
  return __builtin_bit_cast(float, u);
}

__device__ __forceinline__ u32 pack2bf(float a, float b) {
  return (u32)f2bf(a) | ((u32)f2bf(b) << 16);
}

#define MFMA16(a, b, c) __builtin_amdgcn_mfma_f32_16x16x32_bf16(a, b, c, 0, 0, 0)
#define MFMA32(a, b, c) __builtin_amdgcn_mfma_f32_32x32x16_bf16(a, b, c, 0, 0, 0)
#define GLD16(g, l) __builtin_amdgcn_global_load_lds( \
    (const __attribute__((address_space(1))) void*)(g), \
    (__attribute__((address_space(3))) void*)(l), 16, 0, 0)

// ---------------- cast fp32 -> bf16 (vectorized) ----------------
__global__ void k_cast(const float* __restrict__ in, u16* __restrict__ out, int n4) {
  int i = blockIdx.x * blockDim.x + threadIdx.x;
  if (i >= n4) return;
  float4 f = ((const float4*)in)[i];
  ushort4 o;
  o.x = f2bf(f.x); o.y = f2bf(f.y); o.z = f2bf(f.z); o.w = f2bf(f.w);
  ((ushort4*)out)[i] = o;
}

// ---------------- transpose + cast: w[R][C] -> wt[C][R] bf16 ----------------
__global__ void k_transpose_cast(const float* __restrict__ w, u16* __restrict__ wt,
                                 int R, int C) {
  __shared__ float tile[32][33];
  int c0 = blockIdx.x * 32, r0 = blockIdx.y * 32;
  int tx = threadIdx.x, ty = threadIdx.y;  // 32 x 8
  #pragma unroll
  for (int j = 0; j < 32; j += 8)
    tile[ty + j][tx] = w[(size_t)(r0 + ty + j) * C + (c0 + tx)];
  __syncthreads();
  #pragma unroll
  for (int j = 0; j < 32; j += 8)
    wt[(size_t)(c0 + ty + j) * R + (r0 + tx)] = f2bf(tile[tx][ty + j]);
}

// ---------------- 128x128 bf16 MFMA GEMM, K=1024, B given transposed ----------------
template <int EPI>
__global__ __launch_bounds__(256, 2) void k_gemm(
    const u16* __restrict__ A, const u16* __restrict__ Bt,
    const float* __restrict__ bias,
    u16* __restrict__ Qo, u16* __restrict__ Ko, u16* __restrict__ Vt,
    float* __restrict__ outp) {
  __shared__ __align__(16) u16 ldsA[128 * 64];
  __shared__ __align__(16) u16 ldsB[128 * 64];
  const int tid = threadIdx.x;
  const int w = tid >> 6, lane = tid & 63;
  const int wm = w >> 1, wn = w & 1;
  const int m0 = blockIdx.x * 128, n0 = blockIdx.y * 128;
  const int rq = lane & 15, g = lane >> 4;

  const int srow = lane >> 3;
  const int scol = ((lane & 7) ^ srow) << 3;

  f32x4 acc[4][4] = {};
  char* ldsAb = (char*)ldsA;
  char* ldsBb = (char*)ldsB;

  for (int k0 = 0; k0 < EMB; k0 += 64) {
    #pragma unroll
    for (int it = 0; it < 4; ++it) {
      int t = w * 4 + it;
      int row = t * 8 + srow;
      GLD16(A + (size_t)(m0 + row) * EMB + k0 + scol, ldsAb + t * 1024);
      GLD16(Bt + (size_t)(n0 + row) * EMB + k0 + scol, ldsBb + t * 1024);
    }
    __syncthreads();
    #pragma unroll
    for (int ks = 0; ks < 2; ++ks) {
      bf16x8 af[4], bfr[4];
      #pragma unroll
      for (int i = 0; i < 4; ++i) {
        int rowA = wm * 64 + i * 16 + rq;
        int off = (ks * 64 + (g << 4)) ^ ((rowA & 7) << 4);
        af[i] = *(const bf16x8*)(ldsAb + rowA * 128 + off);
        int rowB = wn * 64 + i * 16 + rq;
        int offb = (ks * 64 + (g << 4)) ^ ((rowB & 7) << 4);
        bfr[i] = *(const bf16x8*)(ldsBb + rowB * 128 + offb);
      }
      #pragma unroll
      for (int mi = 0; mi < 4; ++mi)
        #pragma unroll
        for (int ni = 0; ni < 4; ++ni)
          acc[mi][ni] = MFMA16(af[mi], bfr[ni], acc[mi][ni]);
    }
    __syncthreads();
  }

  #pragma unroll
  for (int ni = 0; ni < 4; ++ni) {
    int col = n0 + wn * 64 + ni * 16 + rq;
    float bv = bias[col];
    if (EPI == 0) {
      int part = col >> 10;
      int hh = (col & 1023) >> 6;
      int d = col & 63;
      #pragma unroll
      for (int mi = 0; mi < 4; ++mi) {
        #pragma unroll
        for (int i = 0; i < 4; ++i) {
          int m = m0 + wm * 64 + mi * 16 + g * 4 + i;
          int b = m >> 11, s = m & 2047;
          u16 val = f2bf(acc[mi][ni][i] + bv);
          size_t bh = (size_t)(b * NH + hh);
          if (part == 0)      Qo[(bh * SEQ + s) * HD + d] = val;
          else if (part == 1) Ko[(bh * SEQ + s) * HD + d] = val;
          else                Vt[(bh * HD + d) * SEQ + s] = val;
        }
      }
    } else {
      #pragma unroll
      for (int mi = 0; mi < 4; ++mi)
        #pragma unroll
        for (int i = 0; i < 4; ++i) {
          int m = m0 + wm * 64 + mi * 16 + g * 4 + i;
          outp[(size_t)m * EMB + col] = acc[mi][ni][i] + bv;
        }
    }
  }
}

// ---------------- flash attention pass 1 ----------------
// gid < 1024 : global task (bh, qt); each wave computes a wave-private
//              key-range partial and stores it to global scratch. No LDS.
// gid >= 1024: 4 independent local-head tasks (<=9 chunks), direct ctx write.
__global__ __launch_bounds__(256, 4) void k_attn(
    const u16* __restrict__ Q, const u16* __restrict__ K,
    const u16* __restrict__ Vt, u16* __restrict__ ctx,
    u16* __restrict__ part) {
  const int w = threadIdx.x >> 6, lane = threadIdx.x & 63;
  const int l31 = lane & 31;
  const int hi = lane >> 5;
  const bool hib = hi != 0;
  const int hi8 = hi * 8, hi4 = hi * 4;

  const int gid = blockIdx.x;
  const bool isglob = gid < 1024;

  int bh, qt, cstart, clen;   // chunk range [cstart, cstart+clen) of 32 keys
  if (isglob) {
    int bg = gid & 15;
    int j = gid >> 4;
    qt = ((j & 3) << 4) | (j >> 2);          // bijective, CU-balanced
    bh = (bg >> 2) * 16 + (bg & 3);
    int L = qt + 1;
    int base = L >> 2, rem = L & 3;
    clen = base + (w < rem ? 1 : 0);
    cstart = w * base + (w < rem ? w : rem);
  } else {
    int lidx = (gid - 1024) * 4 + w;         // 0..3071
    int bl = lidx >> 6;
    bh = (bl / 12) * 16 + 4 + (bl % 12);
    qt = lidx & 63;
    int qb_ = qt * 32;
    int klo = (qb_ > WIN) ? qb_ - WIN : 0;
    cstart = klo >> 5;
    clen = qt + 1 - cstart;
  }

  const int qb = qt * 32;
  const int h = bh & 15;
  const int b = bh >> 4;
  const bool isloc = !isglob;

  const u16* Qp = Q + (size_t)bh * SEQ * HD;
  const u16* Kp = K + (size_t)bh * SEQ * HD;
  const u16* Vp = Vt + (size_t)bh * HD * SEQ;

  const int q = qb + l31;

  // Q as B-operand: col=q (lane&31), k = j*16 + hi*8 + i
  bf16x8 qf[4];
  #pragma unroll
  for (int j = 0; j < 4; ++j)
    qf[j] = *(const bf16x8*)(Qp + (size_t)q * HD + j * 16 + hi8);

  f32x16 oacc[2] = {};
  float m = -__builtin_inff();
  float l = 0.f;

  int kc = cstart * 32;
  for (int it = 0; it < clen; ++it, kc += 32) {
    // S^T = K . Q^T
    f32x16 s = {};
    #pragma unroll
    for (int j = 0; j < 4; ++j) {
      bf16x8 kf = *(const bf16x8*)(Kp + (size_t)(kc + l31) * HD + j * 16 + hi8);
      s = MFMA32(kf, qf[j], s);
    }

    float p[16];
    float cmax = -__builtin_inff();
    #pragma unroll
    for (int r = 0; r < 16; ++r) {
      int key = kc + hi4 + (r & 3) + 8 * (r >> 2);
      float v = s[r] * 0.125f;
      bool msk = (key > q) || (isloc && (q - key > WIN));
      p[r] = msk ? -__builtin_inff() : v;
      cmax = fmaxf(cmax, p[r]);
    }
    cmax = fmaxf(cmax, __shfl_xor(cmax, 32));

    float mu;
    if (__any(cmax > m + 8.f)) {
      float mn = fmaxf(m, cmax);
      mu = (mn == -__builtin_inff()) ? 0.f : mn;
      float f = __expf(((m == -__builtin_inff()) ? mu : m) - mu);
      m = mn;
      l *= f;
      #pragma unroll
      for (int dt = 0; dt < 2; ++dt)
        #pragma unroll
        for (int r = 0; r < 16; ++r)
          oacc[dt][r] *= f;
    } else {
      mu = (m == -__builtin_inff()) ? 0.f : m;
    }

    float psum = 0.f;
    #pragma unroll
    for (int r = 0; r < 16; ++r) {
      p[r] = __expf(p[r] - mu);
      psum += p[r];
    }
    psum += __shfl_xor(psum, 32);
    l += psum;

    // P^T B-fragments: pack own pairs, exchange halves via shfl_xor(32)
    union { u32 u[4]; bf16x8 v; } pbf[2];
    #pragma unroll
    for (int sl = 0; sl < 2; ++sl) {
      int s8 = sl * 8;
      u32 X0 = pack2bf(p[s8 + 0], p[s8 + 1]);
      u32 X1 = pack2bf(p[s8 + 2], p[s8 + 3]);
      u32 X2 = pack2bf(p[s8 + 4], p[s8 + 5]);
      u32 X3 = pack2bf(p[s8 + 6], p[s8 + 7]);
      u32 oX0 = (u32)__shfl_xor((int)X0, 32);
      u32 oX1 = (u32)__shfl_xor((int)X1, 32);
      u32 oX2 = (u32)__shfl_xor((int)X2, 32);
      u32 oX3 = (u32)__shfl_xor((int)X3, 32);
      pbf[sl].u[0] = hib ? oX2 : X0;
      pbf[sl].u[1] = hib ? oX3 : X1;
      pbf[sl].u[2] = hib ? X2 : oX0;
      pbf[sl].u[3] = hib ? X3 : oX1;
    }

    // O^T += V^T . P^T
    #pragma unroll
    for (int dt = 0; dt < 2; ++dt) {
      #pragma unroll
      for (int sl = 0; sl < 2; ++sl) {
        bf16x8 vf = *(const bf16x8*)(Vp + (size_t)(dt * 32 + l31) * SEQ + kc + sl * 16 + hi8);
        oacc[dt] = MFMA32(vf, pbf[sl].v, oacc[dt]);
      }
    }
  }

  if (isglob) {
    // store wave-private partial to global scratch: O^T bf16 [64][32] + m,l f32
    u16* PB = part + (size_t)(gid * 4 + w) * PART_U16;
    #pragma unroll
    for (int dt = 0; dt < 2; ++dt)
      #pragma unroll
      for (int r = 0; r < 16; ++r) {
        int d = dt * 32 + hi4 + (r & 3) + 8 * (r >> 2);
        PB[d * 32 + l31] = f2bf(oacc[dt][r]);
      }
    float* PF = (float*)(PB + 2048);
    if (hi == 0) { PF[l31] = m; PF[32 + l31] = l; }
  } else {
    // direct write
    float linv = 1.f / l;
    #pragma unroll
    for (int dt = 0; dt < 2; ++dt) {
      #pragma unroll
      for (int r = 0; r < 16; ++r) {
        int d = dt * 32 + hi4 + (r & 3) + 8 * (r >> 2);
        int e = h * HD + d;
        ctx[(size_t)(b * SEQ + q) * EMB + e] = f2bf(oacc[dt][r] * linv);
      }
    }
  }
}

// ---------------- flash attention pass 2: merge 4 partials per global task ----
__global__ __launch_bounds__(256, 4) void k_merge(
    const u16* __restrict__ part, u16* __restrict__ ctx) {
  const int t = blockIdx.x;                  // 0..1023, same mapping as pass 1
  const int bg = t & 15;
  const int j = t >> 4;
  const int qt = ((j & 3) << 4) | (j >> 2);
  const int bh = (bg >> 2) * 16 + (bg & 3);
  const int qb = qt * 32;
  const int h = bh & 15;
  const int b = bh >> 4;

  const u16* P0 = part + (size_t)(t * 4 + 0) * PART_U16;
  const u16* P1 = part + (size_t)(t * 4 + 1) * PART_U16;
  const u16* P2 = part + (size_t)(t * 4 + 2) * PART_U16;
  const u16* P3 = part + (size_t)(t * 4 + 3) * PART_U16;
  const float* F0 = (const float*)(P0 + 2048);
  const float* F1 = (const float*)(P1 + 2048);
  const float* F2 = (const float*)(P2 + 2048);
  const float* F3 = (const float*)(P3 + 2048);

  const int tid = threadIdx.x;
  const int dd = tid & 63;
  const int qg = tid >> 6;                   // 0..3
  #pragma unroll
  for (int i = 0; i < 8; ++i) {
    int qq = qg * 8 + i;
    float m0v = F0[qq], m1v = F1[qq], m2v = F2[qq], m3v = F3[qq];
    float M = fmaxf(fmaxf(m0v, m1v), fmaxf(m2v, m3v));
    float w0 = __expf(m0v - M), w1 = __expf(m1v - M);
    float w2 = __expf(m2v - M), w3 = __expf(m3v - M);
    float L = w0 * F0[32 + qq] + w1 * F1[32 + qq] +
              w2 * F2[32 + qq] + w3 * F3[32 + qq];
    float val = w0 * bf2f(P0[dd * 32 + qq]) + w1 * bf2f(P1[dd * 32 + qq]) +
                w2 * bf2f(P2[dd * 32 + qq]) + w3 * bf2f(P3[dd * 32 + qq]);
    int s = qb + qq;
    ctx[(size_t)(b * SEQ + s) * EMB + h * HD + dd] = f2bf(val / L);
  }
}

extern "C" void kernel_launch(void* const* d_in, const int* in_sizes, int n_in,
                              void* d_out, int out_size, void* d_ws, size_t ws_size,
                              hipStream_t stream) {
  const float* x     = (const float*)d_in[0];
  const float* w_qkv = (const float*)d_in[1];
  const float* b_qkv = (const float*)d_in[2];
  const float* w_out = (const float*)d_in[3];
  const float* b_out = (const float*)d_in[4];
  float* out = (float*)d_out;

  char* ws = (char*)d_ws;
  u16* xb    = (u16*)(ws);                   // 16 MiB (dead after k_gemm<0>)
  u16* wqkvT = (u16*)(ws + (16ull << 20));   // 6 MiB  (dead after k_gemm<0>)
  u16* woutT = (u16*)(ws + (22ull << 20));   // 2 MiB
  u16* Qb    = (u16*)(ws + (24ull << 20));   // 16 MiB
  u16* Kb    = (u16*)(ws + (40ull << 20));   // 16 MiB
  u16* Vt    = (u16*)(ws + (56ull << 20));   // 16 MiB
  u16* ctx   = (u16*)(ws + (72ull << 20));   // 16 MiB
  u16* part  = xb;                           // 17 MiB partials, reuses xb+wqkvT

  k_cast<<<(MTOT * EMB / 4) / 256, 256, 0, stream>>>(x, xb, MTOT * EMB / 4);
  dim3 tb(32, 8);
  k_transpose_cast<<<dim3(NQKV / 32, EMB / 32), tb, 0, stream>>>(w_qkv, wqkvT, EMB, NQKV);
  k_transpose_cast<<<dim3(EMB / 32, EMB / 32), tb, 0, stream>>>(w_out, woutT, EMB, EMB);

  k_gemm<0><<<dim3(MTOT / 128, NQKV / 128), 256, 0, stream>>>(
      xb, wqkvT, b_qkv, Qb, Kb, Vt, nullptr);

  k_attn<<<dim3(1024 + 768), 256, 0, stream>>>(Qb, Kb, Vt, ctx, part);
  k_merge<<<dim3(1024), 256, 0, stream>>>(part, ctx);

  k_gemm<1><<<dim3(MTOT / 128, EMB / 128), 256, 0, stream>>>(
      ctx, woutT, b_out, nullptr, nullptr, nullptr, out);
}

// Round 8
// 204.039 us; speedup vs baseline: 2.7382x; 1.0050x over previous
//
#include <hip/hip_runtime.h>
#include <stdint.h>

#define EMB 1024
#define SEQ 2048
#define NB 4
#define NH 16
#define HD 64
#define NGLOB 4
#define WIN 256
#define MTOT (NB*SEQ)   // 8192
#define NQKV (3*EMB)    // 3072

// per-partial: O^T bf16 [64][32] (4096 B) + m[32] f32 + l[32] f32 (256 B)
#define PART_U16 2176   // 4352 bytes in u16 units

typedef __attribute__((ext_vector_type(8))) short bf16x8;
typedef __attribute__((ext_vector_type(4))) float f32x4;
typedef __attribute__((ext_vector_type(16))) float f32x16;
typedef unsigned short u16;
typedef unsigned int u32;

#define CL2 0.18033688011112042f  // 0.125 * log2(e)

#if __has_builtin(__builtin_amdgcn_exp2f)
#define EXP2(x) __builtin_amdgcn_exp2f(x)
#else
#define EXP2(x) exp2f(x)
#endif

__device__ __forceinline__ u16 f2bf(float f) {
  u32 u = __builtin_bit_cast(u32, f);
  u += 0x7fffu + ((u >> 16) & 1u);
  return (u16)(u >> 16);
}

__device__ __forceinline__ float bf2f(u16 v) {
  u32 u = (u32)v << 16;
  return __builtin_bit_cast(float, u);
}

// truncating pack of two f32 -> dword of two bf16 (lo = a, hi = b)
__device__ __forceinline__ u32 packtrunc(float a, float b) {
  u32 ua = __builtin_bit_cast(u32, a);
  u32 ub = __builtin_bit_cast(u32, b);
  return (ua >> 16) | (ub & 0xffff0000u);
}

#define MFMA16(a, b, c) __builtin_amdgcn_mfma_f32_16x16x32_bf16(a, b, c, 0, 0, 0)
#define MFMA32(a, b, c) __builtin_amdgcn_mfma_f32_32x32x16_bf16(a, b, c, 0, 0, 0)
#define GLD16(g, l) __builtin_amdgcn_global_load_lds( \
    (const __attribute__((address_space(1))) void*)(g), \
    (__attribute__((address_space(3))) void*)(l), 16, 0, 0)

// ---------------- cast fp32 -> bf16 (vectorized) ----------------
__global__ void k_cast(const float* __restrict__ in, u16* __restrict__ out, int n4) {
  int i = blockIdx.x * blockDim.x + threadIdx.x;
  if (i >= n4) return;
  float4 f = ((const float4*)in)[i];
  ushort4 o;
  o.x = f2bf(f.x); o.y = f2bf(f.y); o.z = f2bf(f.z); o.w = f2bf(f.w);
  ((ushort4*)out)[i] = o;
}

// ---------------- transpose + cast: w[R][C] -> wt[C][R] bf16 ----------------
__global__ void k_transpose_cast(const float* __restrict__ w, u16* __restrict__ wt,
                                 int R, int C) {
  __shared__ float tile[32][33];
  int c0 = blockIdx.x * 32, r0 = blockIdx.y * 32;
  int tx = threadIdx.x, ty = threadIdx.y;  // 32 x 8
  #pragma unroll
  for (int j = 0; j < 32; j += 8)
    tile[ty + j][tx] = w[(size_t)(r0 + ty + j) * C + (c0 + tx)];
  __syncthreads();
  #pragma unroll
  for (int j = 0; j < 32; j += 8)
    wt[(size_t)(c0 + ty + j) * R + (r0 + tx)] = f2bf(tile[tx][ty + j]);
}

// ---------------- 128x128 bf16 MFMA GEMM, K=1024, B given transposed ----------------
template <int EPI>
__global__ __launch_bounds__(256, 2) void k_gemm(
    const u16* __restrict__ A, const u16* __restrict__ Bt,
    const float* __restrict__ bias,
    u16* __restrict__ Qo, u16* __restrict__ Ko, u16* __restrict__ Vt,
    float* __restrict__ outp) {
  __shared__ __align__(16) u16 ldsA[128 * 64];
  __shared__ __align__(16) u16 ldsB[128 * 64];
  const int tid = threadIdx.x;
  const int w = tid >> 6, lane = tid & 63;
  const int wm = w >> 1, wn = w & 1;
  const int m0 = blockIdx.x * 128, n0 = blockIdx.y * 128;
  const int rq = lane & 15, g = lane >> 4;

  const int srow = lane >> 3;
  const int scol = ((lane & 7) ^ srow) << 3;

  f32x4 acc[4][4] = {};
  char* ldsAb = (char*)ldsA;
  char* ldsBb = (char*)ldsB;

  for (int k0 = 0; k0 < EMB; k0 += 64) {
    #pragma unroll
    for (int it = 0; it < 4; ++it) {
      int t = w * 4 + it;
      int row = t * 8 + srow;
      GLD16(A + (size_t)(m0 + row) * EMB + k0 + scol, ldsAb + t * 1024);
      GLD16(Bt + (size_t)(n0 + row) * EMB + k0 + scol, ldsBb + t * 1024);
    }
    __syncthreads();
    #pragma unroll
    for (int ks = 0; ks < 2; ++ks) {
      bf16x8 af[4], bfr[4];
      #pragma unroll
      for (int i = 0; i < 4; ++i) {
        int rowA = wm * 64 + i * 16 + rq;
        int off = (ks * 64 + (g << 4)) ^ ((rowA & 7) << 4);
        af[i] = *(const bf16x8*)(ldsAb + rowA * 128 + off);
        int rowB = wn * 64 + i * 16 + rq;
        int offb = (ks * 64 + (g << 4)) ^ ((rowB & 7) << 4);
        bfr[i] = *(const bf16x8*)(ldsBb + rowB * 128 + offb);
      }
      #pragma unroll
      for (int mi = 0; mi < 4; ++mi)
        #pragma unroll
        for (int ni = 0; ni < 4; ++ni)
          acc[mi][ni] = MFMA16(af[mi], bfr[ni], acc[mi][ni]);
    }
    __syncthreads();
  }

  #pragma unroll
  for (int ni = 0; ni < 4; ++ni) {
    int col = n0 + wn * 64 + ni * 16 + rq;
    float bv = bias[col];
    if (EPI == 0) {
      int part = col >> 10;
      int hh = (col & 1023) >> 6;
      int d = col & 63;
      #pragma unroll
      for (int mi = 0; mi < 4; ++mi) {
        #pragma unroll
        for (int i = 0; i < 4; ++i) {
          int m = m0 + wm * 64 + mi * 16 + g * 4 + i;
          int b = m >> 11, s = m & 2047;
          u16 val = f2bf(acc[mi][ni][i] + bv);
          size_t bh = (size_t)(b * NH + hh);
          if (part == 0)      Qo[(bh * SEQ + s) * HD + d] = val;
          else if (part == 1) Ko[(bh * SEQ + s) * HD + d] = val;
          else                Vt[(bh * HD + d) * SEQ + s] = val;
        }
      }
    } else {
      #pragma unroll
      for (int mi = 0; mi < 4; ++mi)
        #pragma unroll
        for (int i = 0; i < 4; ++i) {
          int m = m0 + wm * 64 + mi * 16 + g * 4 + i;
          outp[(size_t)m * EMB + col] = acc[mi][ni][i] + bv;
        }
    }
  }
}

// ---------------- flash attention pass 1 ----------------
// gid < 1024 : global task (bh, qt); each wave computes a wave-private
//              key-range partial and stores it to global scratch. No LDS.
// gid >= 1024: 4 independent local-head tasks (<=9 chunks), direct ctx write.
// Softmax tracked in RAW score domain: p = exp2(fma(s, CL2, -m*CL2)).
__global__ __launch_bounds__(256, 4) void k_attn(
    const u16* __restrict__ Q, const u16* __restrict__ K,
    const u16* __restrict__ Vt, u16* __restrict__ ctx,
    u16* __restrict__ part) {
  const int w = threadIdx.x >> 6, lane = threadIdx.x & 63;
  const int l31 = lane & 31;
  const int hi = lane >> 5;
  const bool hib = hi != 0;
  const int hi8 = hi * 8, hi4 = hi * 4;

  const int gid = blockIdx.x;
  const bool isglob = gid < 1024;

  int bh, qt, cstart, clen;   // chunk range [cstart, cstart+clen) of 32 keys
  if (isglob) {
    int bg = gid & 15;
    int j = gid >> 4;
    qt = ((j & 3) << 4) | (j >> 2);          // bijective, CU-balanced
    bh = (bg >> 2) * 16 + (bg & 3);
    int L = qt + 1;
    int base = L >> 2, rem = L & 3;
    clen = base + (w < rem ? 1 : 0);
    cstart = w * base + (w < rem ? w : rem);
  } else {
    int lidx = (gid - 1024) * 4 + w;         // 0..3071
    int bl = lidx >> 6;
    bh = (bl / 12) * 16 + 4 + (bl % 12);
    qt = lidx & 63;
    int qb_ = qt * 32;
    int klo = (qb_ > WIN) ? qb_ - WIN : 0;
    cstart = klo >> 5;
    clen = qt + 1 - cstart;
  }

  const int qb = qt * 32;
  const int h = bh & 15;
  const int b = bh >> 4;
  const bool isloc = !isglob;

  const u16* Qp = Q + (size_t)bh * SEQ * HD;
  const u16* Kp = K + (size_t)bh * SEQ * HD;
  const u16* Vp = Vt + (size_t)bh * HD * SEQ;

  const int q = qb + l31;
  const float NINF = -__builtin_inff();

  // Q as B-operand: col=q (lane&31), k = j*16 + hi*8 + i
  bf16x8 qf[4];
  #pragma unroll
  for (int j = 0; j < 4; ++j)
    qf[j] = *(const bf16x8*)(Qp + (size_t)q * HD + j * 16 + hi8);

  f32x16 oacc[2] = {};
  float m = NINF;
  float l = 0.f;

  int kc = cstart * 32;
  #pragma unroll 2
  for (int it = 0; it < clen; ++it, kc += 32) {
    // S^T = K . Q^T (split accumulators to halve the serial MFMA chain)
    f32x16 s0 = {}, s1 = {};
    {
      bf16x8 kf0 = *(const bf16x8*)(Kp + (size_t)(kc + l31) * HD + 0 + hi8);
      bf16x8 kf1 = *(const bf16x8*)(Kp + (size_t)(kc + l31) * HD + 16 + hi8);
      bf16x8 kf2 = *(const bf16x8*)(Kp + (size_t)(kc + l31) * HD + 32 + hi8);
      bf16x8 kf3 = *(const bf16x8*)(Kp + (size_t)(kc + l31) * HD + 48 + hi8);
      s0 = MFMA32(kf0, qf[0], s0);
      s1 = MFMA32(kf2, qf[2], s1);
      s0 = MFMA32(kf1, qf[1], s0);
      s1 = MFMA32(kf3, qf[3], s1);
    }

    // raw scores + mask (only diagonal / first-window chunk need masking)
    const bool needs_mask = (kc == qb) || (isloc && (qb - kc > 225));
    float p[16];
    float cmax = NINF;
    if (needs_mask) {
      #pragma unroll
      for (int r = 0; r < 16; ++r) {
        int key = kc + hi4 + (r & 3) + 8 * (r >> 2);
        float v = s0[r] + s1[r];
        bool bad = (key > q) || (isloc && (q - key > WIN));
        p[r] = bad ? NINF : v;
        cmax = fmaxf(cmax, p[r]);
      }
    } else {
      #pragma unroll
      for (int r = 0; r < 16; ++r) {
        p[r] = s0[r] + s1[r];
        cmax = fmaxf(cmax, p[r]);
      }
    }
    cmax = fmaxf(cmax, __shfl_xor(cmax, 32));

    // defer-max (raw-domain threshold 64 == 8 nats)
    float muC;
    if (__any(cmax > m + 64.f)) {
      float mn = fmaxf(m, cmax);
      muC = (mn == NINF) ? 0.f : mn * CL2;
      float oldC = (m == NINF) ? muC : m * CL2;
      float f = EXP2(oldC - muC);
      m = mn;
      l *= f;
      #pragma unroll
      for (int dt = 0; dt < 2; ++dt)
        #pragma unroll
        for (int r = 0; r < 16; ++r)
          oacc[dt][r] *= f;
    } else {
      muC = (m == NINF) ? 0.f : m * CL2;
    }

    float psum = 0.f;
    #pragma unroll
    for (int r = 0; r < 16; ++r) {
      float e = EXP2(__builtin_fmaf(p[r], CL2, -muC));
      p[r] = e;
      psum += e;
    }
    psum += __shfl_xor(psum, 32);
    l += psum;

    // P^T B-fragments: pack own pairs, exchange halves via shfl_xor(32)
    union { u32 u[4]; bf16x8 v; } pbf[2];
    #pragma unroll
    for (int sl = 0; sl < 2; ++sl) {
      int s8 = sl * 8;
      u32 X0 = packtrunc(p[s8 + 0], p[s8 + 1]);
      u32 X1 = packtrunc(p[s8 + 2], p[s8 + 3]);
      u32 X2 = packtrunc(p[s8 + 4], p[s8 + 5]);
      u32 X3 = packtrunc(p[s8 + 6], p[s8 + 7]);
      u32 oX0 = (u32)__shfl_xor((int)X0, 32);
      u32 oX1 = (u32)__shfl_xor((int)X1, 32);
      u32 oX2 = (u32)__shfl_xor((int)X2, 32);
      u32 oX3 = (u32)__shfl_xor((int)X3, 32);
      pbf[sl].u[0] = hib ? oX2 : X0;
      pbf[sl].u[1] = hib ? oX3 : X1;
      pbf[sl].u[2] = hib ? X2 : oX0;
      pbf[sl].u[3] = hib ? X3 : oX1;
    }

    // O^T += V^T . P^T
    #pragma unroll
    for (int dt = 0; dt < 2; ++dt) {
      #pragma unroll
      for (int sl = 0; sl < 2; ++sl) {
        bf16x8 vf = *(const bf16x8*)(Vp + (size_t)(dt * 32 + l31) * SEQ + kc + sl * 16 + hi8);
        oacc[dt] = MFMA32(vf, pbf[sl].v, oacc[dt]);
      }
    }
  }

  if (isglob) {
    // store wave-private partial to global scratch: O^T bf16 [64][32] + m,l f32
    u16* PB = part + (size_t)(gid * 4 + w) * PART_U16;
    #pragma unroll
    for (int dt = 0; dt < 2; ++dt)
      #pragma unroll
      for (int r = 0; r < 16; ++r) {
        int d = dt * 32 + hi4 + (r & 3) + 8 * (r >> 2);
        PB[d * 32 + l31] = f2bf(oacc[dt][r]);
      }
    float* PF = (float*)(PB + 2048);
    if (hi == 0) { PF[l31] = m; PF[32 + l31] = l; }
  } else {
    // direct write
    float linv = 1.f / l;
    #pragma unroll
    for (int dt = 0; dt < 2; ++dt) {
      #pragma unroll
      for (int r = 0; r < 16; ++r) {
        int d = dt * 32 + hi4 + (r & 3) + 8 * (r >> 2);
        int e = h * HD + d;
        ctx[(size_t)(b * SEQ + q) * EMB + e] = f2bf(oacc[dt][r] * linv);
      }
    }
  }
}

// ---------------- flash attention pass 2: merge 4 partials per global task ----
// partial m values are RAW scores; weights use exp((m_i - M) * 0.125).
__global__ __launch_bounds__(256, 4) void k_merge(
    const u16* __restrict__ part, u16* __restrict__ ctx) {
  const int t = blockIdx.x;                  // 0..1023, same mapping as pass 1
  const int bg = t & 15;
  const int j = t >> 4;
  const int qt = ((j & 3) << 4) | (j >> 2);
  const int bh = (bg >> 2) * 16 + (bg & 3);
  const int qb = qt * 32;
  const int h = bh & 15;
  const int b = bh >> 4;

  const u16* P0 = part + (size_t)(t * 4 + 0) * PART_U16;
  const u16* P1 = part + (size_t)(t * 4 + 1) * PART_U16;
  const u16* P2 = part + (size_t)(t * 4 + 2) * PART_U16;
  const u16* P3 = part + (size_t)(t * 4 + 3) * PART_U16;
  const float* F0 = (const float*)(P0 + 2048);
  const float* F1 = (const float*)(P1 + 2048);
  const float* F2 = (const float*)(P2 + 2048);
  const float* F3 = (const float*)(P3 + 2048);

  const int tid = threadIdx.x;
  const int dd = tid & 63;
  const int qg = tid >> 6;                   // 0..3
  #pragma unroll
  for (int i = 0; i < 8; ++i) {
    int qq = qg * 8 + i;
    float m0v = F0[qq], m1v = F1[qq], m2v = F2[qq], m3v = F3[qq];
    float M = fmaxf(fmaxf(m0v, m1v), fmaxf(m2v, m3v));
    float w0 = __expf((m0v - M) * 0.125f), w1 = __expf((m1v - M) * 0.125f);
    float w2 = __expf((m2v - M) * 0.125f), w3 = __expf((m3v - M) * 0.125f);
    float L = w0 * F0[32 + qq] + w1 * F1[32 + qq] +
              w2 * F2[32 + qq] + w3 * F3[32 + qq];
    float val = w0 * bf2f(P0[dd * 32 + qq]) + w1 * bf2f(P1[dd * 32 + qq]) +
                w2 * bf2f(P2[dd * 32 + qq]) + w3 * bf2f(P3[dd * 32 + qq]);
    int s = qb + qq;
    ctx[(size_t)(b * SEQ + s) * EMB + h * HD + dd] = f2bf(val / L);
  }
}

extern "C" void kernel_launch(void* const* d_in, const int* in_sizes, int n_in,
                              void* d_out, int out_size, void* d_ws, size_t ws_size,
                              hipStream_t stream) {
  const float* x     = (const float*)d_in[0];
  const float* w_qkv = (const float*)d_in[1];
  const float* b_qkv = (const float*)d_in[2];
  const float* w_out = (const float*)d_in[3];
  const float* b_out = (const float*)d_in[4];
  float* out = (float*)d_out;

  char* ws = (char*)d_ws;
  u16* xb    = (u16*)(ws);                   // 16 MiB (dead after k_gemm<0>)
  u16* wqkvT = (u16*)(ws + (16ull << 20));   // 6 MiB  (dead after k_gemm<0>)
  u16* woutT = (u16*)(ws + (22ull << 20));   // 2 MiB
  u16* Qb    = (u16*)(ws + (24ull << 20));   // 16 MiB
  u16* Kb    = (u16*)(ws + (40ull << 20));   // 16 MiB
  u16* Vt    = (u16*)(ws + (56ull << 20));   // 16 MiB
  u16* ctx   = (u16*)(ws + (72ull << 20));   // 16 MiB
  u16* part  = xb;                           // 17 MiB partials, reuses xb+wqkvT

  k_cast<<<(MTOT * EMB / 4) / 256, 256, 0, stream>>>(x, xb, MTOT * EMB / 4);
  dim3 tb(32, 8);
  k_transpose_cast<<<dim3(NQKV / 32, EMB / 32), tb, 0, stream>>>(w_qkv, wqkvT, EMB, NQKV);
  k_transpose_cast<<<dim3(EMB / 32, EMB / 32), tb, 0, stream>>>(w_out, woutT, EMB, EMB);

  k_gemm<0><<<dim3(MTOT / 128, NQKV / 128), 256, 0, stream>>>(
      xb, wqkvT, b_qkv, Qb, Kb, Vt, nullptr);

  k_attn<<<dim3(1024 + 768), 256, 0, stream>>>(Qb, Kb, Vt, ctx, part);
  k_merge<<<dim3(1024), 256, 0, stream>>>(part, ctx);

  k_gemm<1><<<dim3(MTOT / 128, EMB / 128), 256, 0, stream>>>(
      ctx, woutT, b_out, nullptr, nullptr, nullptr, out);
}

// Round 9
// 197.633 us; speedup vs baseline: 2.8270x; 1.0324x over previous
//
#include <hip/hip_runtime.h>
#include <stdint.h>

#define EMB 1024
#define SEQ 2048
#define NB 4
#define NH 16
#define HD 64
#define NGLOB 4
#define WIN 256
#define MTOT (NB*SEQ)   // 8192
#define NQKV (3*EMB)    // 3072

// per-partial: O^T bf16 [64][32] (4096 B) + m[32] f32 + l[32] f32 (256 B)
#define PART_U16 2176   // 4352 bytes in u16 units

typedef __attribute__((ext_vector_type(8))) short bf16x8;
typedef __attribute__((ext_vector_type(4))) float f32x4;
typedef __attribute__((ext_vector_type(16))) float f32x16;
typedef unsigned short u16;
typedef unsigned int u32;

#define CL2 0.18033688011112042f  // 0.125 * log2(e)

#if __has_builtin(__builtin_amdgcn_exp2f)
#define EXP2(x) __builtin_amdgcn_exp2f(x)
#else
#define EXP2(x) exp2f(x)
#endif

__device__ __forceinline__ u16 f2bf(float f) {
  u32 u = __builtin_bit_cast(u32, f);
  u += 0x7fffu + ((u >> 16) & 1u);
  return (u16)(u >> 16);
}

__device__ __forceinline__ float bf2f(u16 v) {
  u32 u = (u32)v << 16;
  return __builtin_bit_cast(float, u);
}

// truncating pack of two f32 -> dword of two bf16 (lo = a, hi = b)
__device__ __forceinline__ u32 packtrunc(float a, float b) {
  u32 ua = __builtin_bit_cast(u32, a);
  u32 ub = __builtin_bit_cast(u32, b);
  return (ua >> 16) | (ub & 0xffff0000u);
}

#define MFMA16(a, b, c) __builtin_amdgcn_mfma_f32_16x16x32_bf16(a, b, c, 0, 0, 0)
#define MFMA32(a, b, c) __builtin_amdgcn_mfma_f32_32x32x16_bf16(a, b, c, 0, 0, 0)
#define GLD16(g, l) __builtin_amdgcn_global_load_lds( \
    (const __attribute__((address_space(1))) void*)(g), \
    (__attribute__((address_space(3))) void*)(l), 16, 0, 0)

// ---------------- cast fp32 -> bf16 (vectorized) ----------------
__global__ void k_cast(const float* __restrict__ in, u16* __restrict__ out, int n4) {
  int i = blockIdx.x * blockDim.x + threadIdx.x;
  if (i >= n4) return;
  float4 f = ((const float4*)in)[i];
  ushort4 o;
  o.x = f2bf(f.x); o.y = f2bf(f.y); o.z = f2bf(f.z); o.w = f2bf(f.w);
  ((ushort4*)out)[i] = o;
}

// ---------------- transpose + cast: w[R][C] -> wt[C][R] bf16 ----------------
__global__ void k_transpose_cast(const float* __restrict__ w, u16* __restrict__ wt,
                                 int R, int C) {
  __shared__ float tile[32][33];
  int c0 = blockIdx.x * 32, r0 = blockIdx.y * 32;
  int tx = threadIdx.x, ty = threadIdx.y;  // 32 x 8
  #pragma unroll
  for (int j = 0; j < 32; j += 8)
    tile[ty + j][tx] = w[(size_t)(r0 + ty + j) * C + (c0 + tx)];
  __syncthreads();
  #pragma unroll
  for (int j = 0; j < 32; j += 8)
    wt[(size_t)(c0 + ty + j) * R + (r0 + tx)] = f2bf(tile[tx][ty + j]);
}

// ---------------- 128x128 bf16 MFMA GEMM, K=1024, B given transposed ----------------
// EPI==0 epilogue: Q [bh][s][d], K [bh][s][d], V 16-key-blocked transpose
//                  Vf[bh][s>>4][d][s&15] (coalesced PV A-fragment loads).
template <int EPI>
__global__ __launch_bounds__(256, 2) void k_gemm(
    const u16* __restrict__ A, const u16* __restrict__ Bt,
    const float* __restrict__ bias,
    u16* __restrict__ Qo, u16* __restrict__ Ko, u16* __restrict__ Vt,
    float* __restrict__ outp) {
  __shared__ __align__(16) u16 ldsA[128 * 64];
  __shared__ __align__(16) u16 ldsB[128 * 64];
  const int tid = threadIdx.x;
  const int w = tid >> 6, lane = tid & 63;
  const int wm = w >> 1, wn = w & 1;
  const int m0 = blockIdx.x * 128, n0 = blockIdx.y * 128;
  const int rq = lane & 15, g = lane >> 4;

  const int srow = lane >> 3;
  const int scol = ((lane & 7) ^ srow) << 3;

  f32x4 acc[4][4] = {};
  char* ldsAb = (char*)ldsA;
  char* ldsBb = (char*)ldsB;

  for (int k0 = 0; k0 < EMB; k0 += 64) {
    #pragma unroll
    for (int it = 0; it < 4; ++it) {
      int t = w * 4 + it;
      int row = t * 8 + srow;
      GLD16(A + (size_t)(m0 + row) * EMB + k0 + scol, ldsAb + t * 1024);
      GLD16(Bt + (size_t)(n0 + row) * EMB + k0 + scol, ldsBb + t * 1024);
    }
    __syncthreads();
    #pragma unroll
    for (int ks = 0; ks < 2; ++ks) {
      bf16x8 af[4], bfr[4];
      #pragma unroll
      for (int i = 0; i < 4; ++i) {
        int rowA = wm * 64 + i * 16 + rq;
        int off = (ks * 64 + (g << 4)) ^ ((rowA & 7) << 4);
        af[i] = *(const bf16x8*)(ldsAb + rowA * 128 + off);
        int rowB = wn * 64 + i * 16 + rq;
        int offb = (ks * 64 + (g << 4)) ^ ((rowB & 7) << 4);
        bfr[i] = *(const bf16x8*)(ldsBb + rowB * 128 + offb);
      }
      #pragma unroll
      for (int mi = 0; mi < 4; ++mi)
        #pragma unroll
        for (int ni = 0; ni < 4; ++ni)
          acc[mi][ni] = MFMA16(af[mi], bfr[ni], acc[mi][ni]);
    }
    __syncthreads();
  }

  #pragma unroll
  for (int ni = 0; ni < 4; ++ni) {
    int col = n0 + wn * 64 + ni * 16 + rq;
    float bv = bias[col];
    if (EPI == 0) {
      int part = col >> 10;
      int hh = (col & 1023) >> 6;
      int d = col & 63;
      #pragma unroll
      for (int mi = 0; mi < 4; ++mi) {
        #pragma unroll
        for (int i = 0; i < 4; ++i) {
          int m = m0 + wm * 64 + mi * 16 + g * 4 + i;
          int b = m >> 11, s = m & 2047;
          u16 val = f2bf(acc[mi][ni][i] + bv);
          size_t bh = (size_t)(b * NH + hh);
          if (part == 0)      Qo[(bh * SEQ + s) * HD + d] = val;
          else if (part == 1) Ko[(bh * SEQ + s) * HD + d] = val;
          else                Vt[((bh * 128 + (s >> 4)) * 64 + d) * 16 + (s & 15)] = val;
        }
      }
    } else {
      #pragma unroll
      for (int mi = 0; mi < 4; ++mi)
        #pragma unroll
        for (int i = 0; i < 4; ++i) {
          int m = m0 + wm * 64 + mi * 16 + g * 4 + i;
          outp[(size_t)m * EMB + col] = acc[mi][ni][i] + bv;
        }
    }
  }
}

// ---------------- flash attention pass 1 ----------------
// gid < 1024 : global task (bh, qt); each wave computes a wave-private
//              key-range partial and stores it to global scratch. No LDS.
// gid >= 1024: 4 independent local-head tasks (<=9 chunks), direct ctx write.
// Softmax tracked in RAW score domain: p = exp2(fma(s, CL2, -m*CL2)).
// V is 16-key-blocked: Vf[bh][s>>4][d][s&15] -> each PV fragment load is a
// 2KiB-contiguous wave access. V fragments issued early (hide under softmax).
__global__ __launch_bounds__(256, 4) void k_attn(
    const u16* __restrict__ Q, const u16* __restrict__ K,
    const u16* __restrict__ Vt, u16* __restrict__ ctx,
    u16* __restrict__ part) {
  const int w = threadIdx.x >> 6, lane = threadIdx.x & 63;
  const int l31 = lane & 31;
  const int hi = lane >> 5;
  const bool hib = hi != 0;
  const int hi8 = hi * 8, hi4 = hi * 4;

  const int gid = blockIdx.x;
  const bool isglob = gid < 1024;

  int bh, qt, cstart, clen;   // chunk range [cstart, cstart+clen) of 32 keys
  if (isglob) {
    int bg = gid & 15;
    int j = gid >> 4;
    qt = ((j & 3) << 4) | (j >> 2);          // bijective, CU-balanced
    bh = (bg >> 2) * 16 + (bg & 3);
    int L = qt + 1;
    int base = L >> 2, rem = L & 3;
    clen = base + (w < rem ? 1 : 0);
    cstart = w * base + (w < rem ? w : rem);
  } else {
    int lidx = (gid - 1024) * 4 + w;         // 0..3071
    int bl = lidx >> 6;
    bh = (bl / 12) * 16 + 4 + (bl % 12);
    qt = lidx & 63;
    int qb_ = qt * 32;
    int klo = (qb_ > WIN) ? qb_ - WIN : 0;
    cstart = klo >> 5;
    clen = qt + 1 - cstart;
  }

  const int qb = qt * 32;
  const int h = bh & 15;
  const int b = bh >> 4;
  const bool isloc = !isglob;

  const u16* Qp = Q + (size_t)bh * SEQ * HD;
  const u16* Kp = K + (size_t)bh * SEQ * HD;
  const u16* Vp = Vt + (size_t)bh * SEQ * HD;   // 16-key-blocked layout

  const int q = qb + l31;
  const float NINF = -__builtin_inff();

  // Q as B-operand: col=q (lane&31), k = j*16 + hi*8 + i
  bf16x8 qf[4];
  #pragma unroll
  for (int j = 0; j < 4; ++j)
    qf[j] = *(const bf16x8*)(Qp + (size_t)q * HD + j * 16 + hi8);

  f32x16 oacc[2] = {};
  float m = NINF;
  float l = 0.f;

  int kc = cstart * 32;
  #pragma unroll 2
  for (int it = 0; it < clen; ++it, kc += 32) {
    // K fragments + early V fragments (independent of softmax -> overlap)
    bf16x8 kf0, kf1, kf2, kf3, vf[2][2];
    {
      const u16* Kr = Kp + (size_t)(kc + l31) * HD + hi8;
      kf0 = *(const bf16x8*)(Kr);
      kf1 = *(const bf16x8*)(Kr + 16);
      kf2 = *(const bf16x8*)(Kr + 32);
      kf3 = *(const bf16x8*)(Kr + 48);
      const u16* Vb = Vp + (size_t)(kc >> 4) * 1024 + hi8;
      #pragma unroll
      for (int dt = 0; dt < 2; ++dt)
        #pragma unroll
        for (int sl = 0; sl < 2; ++sl)
          vf[dt][sl] = *(const bf16x8*)(Vb + (sl * 64 + dt * 32 + l31) * 16);
    }

    // S^T = K . Q^T (split accumulators to halve the serial MFMA chain)
    f32x16 s0 = {}, s1 = {};
    s0 = MFMA32(kf0, qf[0], s0);
    s1 = MFMA32(kf2, qf[2], s1);
    s0 = MFMA32(kf1, qf[1], s0);
    s1 = MFMA32(kf3, qf[3], s1);

    // raw scores + mask (only diagonal / first-window chunk need masking)
    const bool needs_mask = (kc == qb) || (isloc && (qb - kc > 225));
    float p[16];
    float cmax = NINF;
    if (needs_mask) {
      #pragma unroll
      for (int r = 0; r < 16; ++r) {
        int key = kc + hi4 + (r & 3) + 8 * (r >> 2);
        float v = s0[r] + s1[r];
        bool bad = (key > q) || (isloc && (q - key > WIN));
        p[r] = bad ? NINF : v;
        cmax = fmaxf(cmax, p[r]);
      }
    } else {
      #pragma unroll
      for (int r = 0; r < 16; ++r) {
        p[r] = s0[r] + s1[r];
        cmax = fmaxf(cmax, p[r]);
      }
    }
    cmax = fmaxf(cmax, __shfl_xor(cmax, 32));

    // defer-max (raw-domain threshold 64 == 8 nats)
    float muC;
    if (__any(cmax > m + 64.f)) {
      float mn = fmaxf(m, cmax);
      muC = (mn == NINF) ? 0.f : mn * CL2;
      float oldC = (m == NINF) ? muC : m * CL2;
      float f = EXP2(oldC - muC);
      m = mn;
      l *= f;
      #pragma unroll
      for (int dt = 0; dt < 2; ++dt)
        #pragma unroll
        for (int r = 0; r < 16; ++r)
          oacc[dt][r] *= f;
    } else {
      muC = (m == NINF) ? 0.f : m * CL2;
    }

    float psum = 0.f;
    #pragma unroll
    for (int r = 0; r < 16; ++r) {
      float e = EXP2(__builtin_fmaf(p[r], CL2, -muC));
      p[r] = e;
      psum += e;
    }
    psum += __shfl_xor(psum, 32);
    l += psum;

    // P^T B-fragments: pack own pairs, exchange halves via shfl_xor(32)
    union { u32 u[4]; bf16x8 v; } pbf[2];
    #pragma unroll
    for (int sl = 0; sl < 2; ++sl) {
      int s8 = sl * 8;
      u32 X0 = packtrunc(p[s8 + 0], p[s8 + 1]);
      u32 X1 = packtrunc(p[s8 + 2], p[s8 + 3]);
      u32 X2 = packtrunc(p[s8 + 4], p[s8 + 5]);
      u32 X3 = packtrunc(p[s8 + 6], p[s8 + 7]);
      u32 oX0 = (u32)__shfl_xor((int)X0, 32);
      u32 oX1 = (u32)__shfl_xor((int)X1, 32);
      u32 oX2 = (u32)__shfl_xor((int)X2, 32);
      u32 oX3 = (u32)__shfl_xor((int)X3, 32);
      pbf[sl].u[0] = hib ? oX2 : X0;
      pbf[sl].u[1] = hib ? oX3 : X1;
      pbf[sl].u[2] = hib ? X2 : oX0;
      pbf[sl].u[3] = hib ? X3 : oX1;
    }

    // O^T += V^T . P^T
    #pragma unroll
    for (int dt = 0; dt < 2; ++dt)
      #pragma unroll
      for (int sl = 0; sl < 2; ++sl)
        oacc[dt] = MFMA32(vf[dt][sl], pbf[sl].v, oacc[dt]);
  }

  if (isglob) {
    // store wave-private partial to global scratch: O^T bf16 [64][32] + m,l f32
    u16* PB = part + (size_t)(gid * 4 + w) * PART_U16;
    #pragma unroll
    for (int dt = 0; dt < 2; ++dt)
      #pragma unroll
      for (int r = 0; r < 16; ++r) {
        int d = dt * 32 + hi4 + (r & 3) + 8 * (r >> 2);
        PB[d * 32 + l31] = f2bf(oacc[dt][r]);
      }
    float* PF = (float*)(PB + 2048);
    if (hi == 0) { PF[l31] = m; PF[32 + l31] = l; }
  } else {
    // direct write
    float linv = 1.f / l;
    #pragma unroll
    for (int dt = 0; dt < 2; ++dt) {
      #pragma unroll
      for (int r = 0; r < 16; ++r) {
        int d = dt * 32 + hi4 + (r & 3) + 8 * (r >> 2);
        int e = h * HD + d;
        ctx[(size_t)(b * SEQ + q) * EMB + e] = f2bf(oacc[dt][r] * linv);
      }
    }
  }
}

// ---------------- flash attention pass 2: merge 4 partials per global task ----
// partial m values are RAW scores; weights use exp((m_i - M) * 0.125).
__global__ __launch_bounds__(256, 4) void k_merge(
    const u16* __restrict__ part, u16* __restrict__ ctx) {
  const int t = blockIdx.x;                  // 0..1023, same mapping as pass 1
  const int bg = t & 15;
  const int j = t >> 4;
  const int qt = ((j & 3) << 4) | (j >> 2);
  const int bh = (bg >> 2) * 16 + (bg & 3);
  const int qb = qt * 32;
  const int h = bh & 15;
  const int b = bh >> 4;

  const u16* P0 = part + (size_t)(t * 4 + 0) * PART_U16;
  const u16* P1 = part + (size_t)(t * 4 + 1) * PART_U16;
  const u16* P2 = part + (size_t)(t * 4 + 2) * PART_U16;
  const u16* P3 = part + (size_t)(t * 4 + 3) * PART_U16;
  const float* F0 = (const float*)(P0 + 2048);
  const float* F1 = (const float*)(P1 + 2048);
  const float* F2 = (const float*)(P2 + 2048);
  const float* F3 = (const float*)(P3 + 2048);

  const int tid = threadIdx.x;
  const int dd = tid & 63;
  const int qg = tid >> 6;                   // 0..3
  #pragma unroll
  for (int i = 0; i < 8; ++i) {
    int qq = qg * 8 + i;
    float m0v = F0[qq], m1v = F1[qq], m2v = F2[qq], m3v = F3[qq];
    float M = fmaxf(fmaxf(m0v, m1v), fmaxf(m2v, m3v));
    float w0 = __expf((m0v - M) * 0.125f), w1 = __expf((m1v - M) * 0.125f);
    float w2 = __expf((m2v - M) * 0.125f), w3 = __expf((m3v - M) * 0.125f);
    float L = w0 * F0[32 + qq] + w1 * F1[32 + qq] +
              w2 * F2[32 + qq] + w3 * F3[32 + qq];
    float val = w0 * bf2f(P0[dd * 32 + qq]) + w1 * bf2f(P1[dd * 32 + qq]) +
                w2 * bf2f(P2[dd * 32 + qq]) + w3 * bf2f(P3[dd * 32 + qq]);
    int s = qb + qq;
    ctx[(size_t)(b * SEQ + s) * EMB + h * HD + dd] = f2bf(val / L);
  }
}

extern "C" void kernel_launch(void* const* d_in, const int* in_sizes, int n_in,
                              void* d_out, int out_size, void* d_ws, size_t ws_size,
                              hipStream_t stream) {
  const float* x     = (const float*)d_in[0];
  const float* w_qkv = (const float*)d_in[1];
  const float* b_qkv = (const float*)d_in[2];
  const float* w_out = (const float*)d_in[3];
  const float* b_out = (const float*)d_in[4];
  float* out = (float*)d_out;

  char* ws = (char*)d_ws;
  u16* xb    = (u16*)(ws);                   // 16 MiB (dead after k_gemm<0>)
  u16* wqkvT = (u16*)(ws + (16ull << 20));   // 6 MiB  (dead after k_gemm<0>)
  u16* woutT = (u16*)(ws + (22ull << 20));   // 2 MiB
  u16* Qb    = (u16*)(ws + (24ull << 20));   // 16 MiB
  u16* Kb    = (u16*)(ws + (40ull << 20));   // 16 MiB
  u16* Vt    = (u16*)(ws + (56ull << 20));   // 16 MiB (16-key-blocked layout)
  u16* ctx   = (u16*)(ws + (72ull << 20));   // 16 MiB
  u16* part  = xb;                           // 17 MiB partials, reuses xb+wqkvT

  k_cast<<<(MTOT * EMB / 4) / 256, 256, 0, stream>>>(x, xb, MTOT * EMB / 4);
  dim3 tb(32, 8);
  k_transpose_cast<<<dim3(NQKV / 32, EMB / 32), tb, 0, stream>>>(w_qkv, wqkvT, EMB, NQKV);
  k_transpose_cast<<<dim3(EMB / 32, EMB / 32), tb, 0, stream>>>(w_out, woutT, EMB, EMB);

  k_gemm<0><<<dim3(MTOT / 128, NQKV / 128), 256, 0, stream>>>(
      xb, wqkvT, b_qkv, Qb, Kb, Vt, nullptr);

  k_attn<<<dim3(1024 + 768), 256, 0, stream>>>(Qb, Kb, Vt, ctx, part);
  k_merge<<<dim3(1024), 256, 0, stream>>>(part, ctx);

  k_gemm<1><<<dim3(MTOT / 128, EMB / 128), 256, 0, stream>>>(
      ctx, woutT, b_out, nullptr, nullptr, nullptr, out);
}